// Round 1
// baseline (948.963 us; speedup 1.0000x reference)
//
#include <hip/hip_runtime.h>

#define N_NODES 100000
#define KK 5
#define CC 16
#define EE 3200000

// Kernel 1: Zt[k*N + n] = sum_c X[n,c] * h[c,k]
__global__ void compute_z_kernel(const float* __restrict__ X,
                                 const float* __restrict__ h,
                                 float* __restrict__ Zt) {
    int n = blockIdx.x * blockDim.x + threadIdx.x;
    if (n >= N_NODES) return;

    const float4* Xr = (const float4*)(X + (size_t)n * CC);
    float4 x0 = Xr[0];
    float4 x1 = Xr[1];
    float4 x2 = Xr[2];
    float4 x3 = Xr[3];
    float xv[CC] = {x0.x, x0.y, x0.z, x0.w,
                    x1.x, x1.y, x1.z, x1.w,
                    x2.x, x2.y, x2.z, x2.w,
                    x3.x, x3.y, x3.z, x3.w};

#pragma unroll
    for (int k = 0; k < KK; ++k) {
        float acc = 0.0f;
#pragma unroll
        for (int c = 0; c < CC; ++c) {
            acc += xv[c] * h[c * KK + k];   // h address is wave-uniform -> s_load
        }
        Zt[k * N_NODES + n] = acc;
    }
}

// Kernel 2: for each edge i (k-major): y[rows[i]] += vals[i] * Zt[k*N + cols[i]]
// 4 edges per thread; E % 4 == 0 and E % 4-groups never straddle a k boundary.
__global__ void edge_kernel(const int* __restrict__ rows,
                            const int* __restrict__ cols,
                            const float* __restrict__ vals,
                            const float* __restrict__ Zt,
                            float* __restrict__ y) {
    int t = blockIdx.x * blockDim.x + threadIdx.x;
    int base = t * 4;                    // < 16,000,000 fits in int32
    if (base >= KK * EE) return;
    int k = base / EE;                   // same k for all 4 edges in the group
    const float* Zk = Zt + (size_t)k * N_NODES;

    int4   r = *(const int4*)(rows + base);
    int4   c = *(const int4*)(cols + base);
    float4 v = *(const float4*)(vals + base);

    atomicAdd(&y[r.x], v.x * Zk[c.x]);
    atomicAdd(&y[r.y], v.y * Zk[c.y]);
    atomicAdd(&y[r.z], v.z * Zk[c.z]);
    atomicAdd(&y[r.w], v.w * Zk[c.w]);
}

extern "C" void kernel_launch(void* const* d_in, const int* in_sizes, int n_in,
                              void* d_out, int out_size, void* d_ws, size_t ws_size,
                              hipStream_t stream) {
    const float* X    = (const float*)d_in[0];
    const int*   rows = (const int*)  d_in[1];
    const int*   cols = (const int*)  d_in[2];
    const float* vals = (const float*)d_in[3];
    const float* h    = (const float*)d_in[4];
    float* y  = (float*)d_out;
    float* Zt = (float*)d_ws;            // K*N*4 = 2 MB scratch

    // y must start at zero (harness poisons d_out with 0xAA)
    hipMemsetAsync(y, 0, (size_t)out_size * sizeof(float), stream);

    {
        int threads = 256;
        int blocks  = (N_NODES + threads - 1) / threads;
        compute_z_kernel<<<blocks, threads, 0, stream>>>(X, h, Zt);
    }
    {
        int threads = 256;
        int total_groups = (KK * EE) / 4;                 // 4M threads
        int blocks = (total_groups + threads - 1) / threads;
        edge_kernel<<<blocks, threads, 0, stream>>>(rows, cols, vals, Zt, y);
    }
}

// Round 2
// 908.557 us; speedup vs baseline: 1.0445x; 1.0445x over previous
//
#include <hip/hip_runtime.h>

#define N_NODES 100000
#define KK 5
#define CC 16
#define EE 3200000
#define NXCC 8

// Physical XCD (chiplet) id of the CU this wave runs on. [measured: learn_hip m09 -> 0..7]
__device__ __forceinline__ int xcc_id() {
    int x;
    asm volatile("s_getreg_b32 %0, hwreg(HW_REG_XCC_ID)" : "=s"(x));
    return x & (NXCC - 1);
}

// Kernel 1: Zt[k*N + n] = sum_c X[n,c] * h[c,k]
__global__ void compute_z_kernel(const float* __restrict__ X,
                                 const float* __restrict__ h,
                                 float* __restrict__ Zt) {
    int n = blockIdx.x * blockDim.x + threadIdx.x;
    if (n >= N_NODES) return;

    const float4* Xr = (const float4*)(X + (size_t)n * CC);
    float4 x0 = Xr[0];
    float4 x1 = Xr[1];
    float4 x2 = Xr[2];
    float4 x3 = Xr[3];
    float xv[CC] = {x0.x, x0.y, x0.z, x0.w,
                    x1.x, x1.y, x1.z, x1.w,
                    x2.x, x2.y, x2.z, x2.w,
                    x3.x, x3.y, x3.z, x3.w};

#pragma unroll
    for (int k = 0; k < KK; ++k) {
        float acc = 0.0f;
#pragma unroll
        for (int c = 0; c < CC; ++c) {
            acc += xv[c] * h[c * KK + k];
        }
        Zt[k * N_NODES + n] = acc;
    }
}

// Kernel 2: y_rep[xcd][rows[i]] += vals[i] * Zt[k*N + cols[i]]
// Workgroup-scope atomics compile WITHOUT sc1 -> RMW executes at the local
// XCD's L2 and the line stays dirty in L2 (no 32 B far-atomic write per op).
// Correct because replica r is only ever touched by blocks on XCD r, and all
// CUs of one XCD share one L2 (the TCC performs the atomic). End-of-dispatch
// release writes the dirty replica lines back for the reduce kernel.
__global__ void edge_kernel(const int* __restrict__ rows,
                            const int* __restrict__ cols,
                            const float* __restrict__ vals,
                            const float* __restrict__ Zt,
                            float* __restrict__ yrep) {
    int t = blockIdx.x * blockDim.x + threadIdx.x;
    int base = t * 4;
    if (base >= KK * EE) return;
    int k = base / EE;                      // 4-edge group never straddles a k boundary
    const float* Zk = Zt + (size_t)k * N_NODES;
    float* y = yrep + (size_t)xcc_id() * N_NODES;

    int4   r = *(const int4*)(rows + base);
    int4   c = *(const int4*)(cols + base);
    float4 v = *(const float4*)(vals + base);

    __hip_atomic_fetch_add(&y[r.x], v.x * Zk[c.x], __ATOMIC_RELAXED, __HIP_MEMORY_SCOPE_WORKGROUP);
    __hip_atomic_fetch_add(&y[r.y], v.y * Zk[c.y], __ATOMIC_RELAXED, __HIP_MEMORY_SCOPE_WORKGROUP);
    __hip_atomic_fetch_add(&y[r.z], v.z * Zk[c.z], __ATOMIC_RELAXED, __HIP_MEMORY_SCOPE_WORKGROUP);
    __hip_atomic_fetch_add(&y[r.w], v.w * Zk[c.w], __ATOMIC_RELAXED, __HIP_MEMORY_SCOPE_WORKGROUP);
}

// Kernel 3: y[n] = sum_r yrep[r][n]
__global__ void reduce_kernel(const float* __restrict__ yrep,
                              float* __restrict__ y) {
    int n = blockIdx.x * blockDim.x + threadIdx.x;
    if (n >= N_NODES) return;
    float acc = 0.0f;
#pragma unroll
    for (int r = 0; r < NXCC; ++r) {
        acc += yrep[(size_t)r * N_NODES + n];
    }
    y[n] = acc;
}

extern "C" void kernel_launch(void* const* d_in, const int* in_sizes, int n_in,
                              void* d_out, int out_size, void* d_ws, size_t ws_size,
                              hipStream_t stream) {
    const float* X    = (const float*)d_in[0];
    const int*   rows = (const int*)  d_in[1];
    const int*   cols = (const int*)  d_in[2];
    const float* vals = (const float*)d_in[3];
    const float* h    = (const float*)d_in[4];
    float* y    = (float*)d_out;
    float* Zt   = (float*)d_ws;                              // 2 MB
    float* yrep = (float*)d_ws + (size_t)KK * N_NODES;       // 8 * 400 KB = 3.2 MB

    // replicas must start at zero (ws is poisoned with 0xAA before every launch)
    hipMemsetAsync(yrep, 0, (size_t)NXCC * N_NODES * sizeof(float), stream);

    {
        int threads = 256;
        int blocks  = (N_NODES + threads - 1) / threads;
        compute_z_kernel<<<blocks, threads, 0, stream>>>(X, h, Zt);
    }
    {
        int threads = 256;
        int total_groups = (KK * EE) / 4;                    // 4M threads
        int blocks = (total_groups + threads - 1) / threads;
        edge_kernel<<<blocks, threads, 0, stream>>>(rows, cols, vals, Zt, yrep);
    }
    {
        int threads = 256;
        int blocks  = (N_NODES + threads - 1) / threads;
        reduce_kernel<<<blocks, threads, 0, stream>>>(yrep, y);
    }
}

// Round 3
// 907.064 us; speedup vs baseline: 1.0462x; 1.0016x over previous
//
#include <hip/hip_runtime.h>

#define N_NODES 100000
#define KK 5
#define CC 16
#define EE 3200000
#define NXCC 8

// Physical XCD (chiplet) id of the CU this wave runs on. [measured: learn_hip m09 -> 0..7]
__device__ __forceinline__ int xcc_id() {
    int x;
    asm volatile("s_getreg_b32 %0, hwreg(HW_REG_XCC_ID)" : "=s"(x));
    return x & (NXCC - 1);
}

// Kernel 1: Zt[k*N + n] = sum_c X[n,c] * h[c,k]
__global__ void compute_z_kernel(const float* __restrict__ X,
                                 const float* __restrict__ h,
                                 float* __restrict__ Zt) {
    int n = blockIdx.x * blockDim.x + threadIdx.x;
    if (n >= N_NODES) return;

    const float4* Xr = (const float4*)(X + (size_t)n * CC);
    float4 x0 = Xr[0];
    float4 x1 = Xr[1];
    float4 x2 = Xr[2];
    float4 x3 = Xr[3];
    float xv[CC] = {x0.x, x0.y, x0.z, x0.w,
                    x1.x, x1.y, x1.z, x1.w,
                    x2.x, x2.y, x2.z, x2.w,
                    x3.x, x3.y, x3.z, x3.w};

#pragma unroll
    for (int k = 0; k < KK; ++k) {
        float acc = 0.0f;
#pragma unroll
        for (int c = 0; c < CC; ++c) {
            acc += xv[c] * h[c * KK + k];
        }
        Zt[k * N_NODES + n] = acc;
    }
}

// Kernel 2: yrep[xcd][rows[i]] += vals[i] * Zt[k*N + cols[i]]
// unsafeAtomicAdd -> native global_atomic_add_f32 (fire-and-forget, no CAS
// retry loop). Per-XCD replicas cut same-address contention 8x.
__global__ void edge_kernel(const int* __restrict__ rows,
                            const int* __restrict__ cols,
                            const float* __restrict__ vals,
                            const float* __restrict__ Zt,
                            float* __restrict__ yrep) {
    int t = blockIdx.x * blockDim.x + threadIdx.x;
    int base = t * 4;
    if (base >= KK * EE) return;
    int k = base / EE;                      // 4-edge group never straddles a k boundary
    const float* Zk = Zt + (size_t)k * N_NODES;
    float* y = yrep + (size_t)xcc_id() * N_NODES;

    int4   r = *(const int4*)(rows + base);
    int4   c = *(const int4*)(cols + base);
    float4 v = *(const float4*)(vals + base);

    unsafeAtomicAdd(&y[r.x], v.x * Zk[c.x]);
    unsafeAtomicAdd(&y[r.y], v.y * Zk[c.y]);
    unsafeAtomicAdd(&y[r.z], v.z * Zk[c.z]);
    unsafeAtomicAdd(&y[r.w], v.w * Zk[c.w]);
}

// Kernel 3: y[n] = sum_r yrep[r][n]
__global__ void reduce_kernel(const float* __restrict__ yrep,
                              float* __restrict__ y) {
    int n = blockIdx.x * blockDim.x + threadIdx.x;
    if (n >= N_NODES) return;
    float acc = 0.0f;
#pragma unroll
    for (int r = 0; r < NXCC; ++r) {
        acc += yrep[(size_t)r * N_NODES + n];
    }
    y[n] = acc;
}

extern "C" void kernel_launch(void* const* d_in, const int* in_sizes, int n_in,
                              void* d_out, int out_size, void* d_ws, size_t ws_size,
                              hipStream_t stream) {
    const float* X    = (const float*)d_in[0];
    const int*   rows = (const int*)  d_in[1];
    const int*   cols = (const int*)  d_in[2];
    const float* vals = (const float*)d_in[3];
    const float* h    = (const float*)d_in[4];
    float* y    = (float*)d_out;
    float* Zt   = (float*)d_ws;                              // 2 MB
    float* yrep = (float*)d_ws + (size_t)KK * N_NODES;       // 8 * 400 KB = 3.2 MB

    // replicas must start at zero (ws is poisoned with 0xAA before every launch)
    hipMemsetAsync(yrep, 0, (size_t)NXCC * N_NODES * sizeof(float), stream);

    {
        int threads = 256;
        int blocks  = (N_NODES + threads - 1) / threads;
        compute_z_kernel<<<blocks, threads, 0, stream>>>(X, h, Zt);
    }
    {
        int threads = 256;
        int total_groups = (KK * EE) / 4;                    // 4M threads
        int blocks = (total_groups + threads - 1) / threads;
        edge_kernel<<<blocks, threads, 0, stream>>>(rows, cols, vals, Zt, yrep);
    }
    {
        int threads = 256;
        int blocks  = (N_NODES + threads - 1) / threads;
        reduce_kernel<<<blocks, threads, 0, stream>>>(yrep, y);
    }
}